// Round 1
// baseline (129.705 us; speedup 1.0000x reference)
//
#include <hip/hip_runtime.h>
#include <math.h>

#define S_LEN 2048
#define NB 4
#define EMB 1024
#define HD 64
#define NROW (NB * S_LEN)

typedef _Float16 half8 __attribute__((ext_vector_type(8)));
typedef float f32x4 __attribute__((ext_vector_type(4)));

static __device__ __forceinline__ f32x4 mfma_16x16x32(half8 a, half8 b, f32x4 c) {
    return __builtin_amdgcn_mfma_f32_16x16x32_f16(a, b, c, 0, 0, 0);
}

// ---------------------------------------------------------------------------
// Kernel 1: QKV projection.  [8192,1024] @ [1024,64] (+bias) for each of q,k,v.
// Split-precision: x -> fp16 hi+lo, W -> fp16 hi+lo, 3-term MFMA (hh + hl + lh)
// gives ~fp32 accuracy.  q,k outputs stored as fp16 hi/lo pairs; v as fp16.
// grid (NROW/64, 3), block 256 (4 waves, each wave 16 rows x 64 cols).
// ---------------------------------------------------------------------------
__global__ __launch_bounds__(256) void proj_kernel(
    const float* __restrict__ x,
    const float* __restrict__ Wq, const float* __restrict__ bq,
    const float* __restrict__ Wk, const float* __restrict__ bk,
    const float* __restrict__ Wv, const float* __restrict__ bv,
    _Float16* __restrict__ qh, _Float16* __restrict__ ql,
    _Float16* __restrict__ kh, _Float16* __restrict__ kl,
    _Float16* __restrict__ vh)
{
    const int g = blockIdx.y;
    const float* W    = (g == 0) ? Wq : (g == 1) ? Wk : Wv;
    const float* bias = (g == 0) ? bq : (g == 1) ? bk : bv;
    _Float16* oh = (g == 0) ? qh : (g == 1) ? kh : vh;
    _Float16* ol = (g == 0) ? ql : (g == 1) ? kl : nullptr;

    const int m0   = blockIdx.x * 64;
    const int t    = threadIdx.x;
    const int lane = t & 63;
    const int w    = t >> 6;

    __shared__ __align__(16) _Float16 xh_lds[64][40];
    __shared__ __align__(16) _Float16 xl_lds[64][40];
    __shared__ __align__(16) _Float16 wth[64][40];   // W^T hi: [col][k]
    __shared__ __align__(16) _Float16 wtl[64][40];   // W^T lo

    f32x4 acc[4] = {f32x4{0,0,0,0}, f32x4{0,0,0,0}, f32x4{0,0,0,0}, f32x4{0,0,0,0}};

    const int xr = t >> 2;        // 0..63: x row in tile
    const int xc = (t & 3) * 8;   // x col chunk (8 of 32)
    const int wc = t & 63;        // W col
    const int wk = (t >> 6) * 8;  // W k chunk (8 of 32)

    const int ar = 16 * w + (lane & 15);
    const int ak = (lane >> 4) * 8;

    for (int k0 = 0; k0 < EMB; k0 += 32) {
        // ---- stage x tile (64 x 32 fp32 -> hi/lo fp16) ----
        const float* xp = x + (size_t)(m0 + xr) * EMB + k0 + xc;
        float xv[8];
        *(f32x4*)&xv[0] = *(const f32x4*)xp;
        *(f32x4*)&xv[4] = *(const f32x4*)(xp + 4);
        half8 hx, lx;
#pragma unroll
        for (int i = 0; i < 8; i++) {
            _Float16 h = (_Float16)xv[i];
            hx[i] = h;
            lx[i] = (_Float16)(xv[i] - (float)h);
        }
        *(half8*)&xh_lds[xr][xc] = hx;
        *(half8*)&xl_lds[xr][xc] = lx;

        // ---- stage W^T tile (32 x 64 fp32 -> hi/lo fp16, transposed) ----
        float wv[8];
#pragma unroll
        for (int i = 0; i < 8; i++) wv[i] = W[(size_t)(k0 + wk + i) * HD + wc];
        half8 hw, lw;
#pragma unroll
        for (int i = 0; i < 8; i++) {
            _Float16 h = (_Float16)wv[i];
            hw[i] = h;
            lw[i] = (_Float16)(wv[i] - (float)h);
        }
        *(half8*)&wth[wc][wk] = hw;
        *(half8*)&wtl[wc][wk] = lw;

        __syncthreads();

        half8 axh = *(const half8*)&xh_lds[ar][ak];
        half8 axl = *(const half8*)&xl_lds[ar][ak];
#pragma unroll
        for (int c = 0; c < 4; c++) {
            const int bc = 16 * c + (lane & 15);
            half8 bwh = *(const half8*)&wth[bc][ak];
            half8 bwl = *(const half8*)&wtl[bc][ak];
            acc[c] = mfma_16x16x32(axh, bwh, acc[c]);
            acc[c] = mfma_16x16x32(axh, bwl, acc[c]);
            acc[c] = mfma_16x16x32(axl, bwh, acc[c]);
        }
        __syncthreads();
    }

    // ---- epilogue: add bias, split hi/lo, store ----
#pragma unroll
    for (int c = 0; c < 4; c++) {
        const int col = 16 * c + (lane & 15);
        const float bb = bias[col];
#pragma unroll
        for (int r = 0; r < 4; r++) {
            const int row = m0 + 16 * w + (lane >> 4) * 4 + r;
            const float val = acc[c][r] + bb;
            const _Float16 h = (_Float16)val;
            oh[(size_t)row * HD + col] = h;
            if (ol) ol[(size_t)row * HD + col] = (_Float16)(val - (float)h);
        }
    }
}

// ---------------------------------------------------------------------------
// Kernel 2: causal flash attention.  QB=64 (4 waves x 16 rows), KVB=32.
// logits tracked as t = (q.k)*8*log2(e); p = exp2(t - m).
// grid (S/64, B), block 256.
// ---------------------------------------------------------------------------
#define SC 11.5415603f  /* 8 * log2(e) */

__global__ __launch_bounds__(256) void attn_kernel(
    const _Float16* __restrict__ qh, const _Float16* __restrict__ ql,
    const _Float16* __restrict__ kh, const _Float16* __restrict__ kl,
    const _Float16* __restrict__ vh, float* __restrict__ out)
{
    const int b    = blockIdx.y;
    const int q0   = blockIdx.x * 64;
    const int t    = threadIdx.x;
    const int lane = t & 63;
    const int w    = t >> 6;

    __shared__ __align__(16) _Float16 klds_h[32][72];
    __shared__ __align__(16) _Float16 klds_l[32][72];
    __shared__ __align__(16) _Float16 vt[64][40];       // V^T: [dim][key]
    __shared__ __align__(16) _Float16 plds[4][16][40];  // per-wave P

    // Q fragments (row = lane%16 of this wave's 16-row strip)
    const size_t rowq = (size_t)(b * S_LEN + q0 + 16 * w + (lane & 15)) * HD;
    half8 aqh[2], aql[2];
#pragma unroll
    for (int h = 0; h < 2; h++) {
        aqh[h] = *(const half8*)(qh + rowq + h * 32 + (lane >> 4) * 8);
        aql[h] = *(const half8*)(ql + rowq + h * 32 + (lane >> 4) * 8);
    }

    f32x4 o[4] = {f32x4{0,0,0,0}, f32x4{0,0,0,0}, f32x4{0,0,0,0}, f32x4{0,0,0,0}};
    float m_r[4], l_r[4];
#pragma unroll
    for (int r = 0; r < 4; r++) { m_r[r] = -__builtin_inff(); l_r[r] = 0.f; }

    const int nt = (q0 + 64) / 32;
    const int sk = t >> 3;        // staging key 0..31
    const int sd = (t & 7) * 8;   // staging dim chunk

    for (int tile = 0; tile < nt; tile++) {
        const int kv0 = tile * 32;
        // ---- stage K hi/lo and V^T ----
        const size_t krow = (size_t)(b * S_LEN + kv0 + sk) * HD + sd;
        *(half8*)&klds_h[sk][sd] = *(const half8*)(kh + krow);
        *(half8*)&klds_l[sk][sd] = *(const half8*)(kl + krow);
        half8 vv = *(const half8*)(vh + krow);
#pragma unroll
        for (int i = 0; i < 8; i++) vt[sd + i][sk] = vv[i];
        __syncthreads();

        // ---- QK^T (3-term split) ----
        f32x4 s[2] = {f32x4{0,0,0,0}, f32x4{0,0,0,0}};
#pragma unroll
        for (int f = 0; f < 2; f++) {
            const int key = 16 * f + (lane & 15);
#pragma unroll
            for (int h = 0; h < 2; h++) {
                half8 bkh = *(const half8*)&klds_h[key][h * 32 + (lane >> 4) * 8];
                half8 bkl = *(const half8*)&klds_l[key][h * 32 + (lane >> 4) * 8];
                s[f] = mfma_16x16x32(aqh[h], bkh, s[f]);
                s[f] = mfma_16x16x32(aqh[h], bkl, s[f]);
                s[f] = mfma_16x16x32(aql[h], bkh, s[f]);
            }
        }

        // ---- mask + online softmax ----
        float p0[4], p1[4], corr[4];
#pragma unroll
        for (int r = 0; r < 4; r++) {
            const int qrow = q0 + 16 * w + (lane >> 4) * 4 + r;
            const int key0 = kv0 + (lane & 15);
            const int key1 = kv0 + 16 + (lane & 15);
            float t0 = (key0 <= qrow) ? s[0][r] * SC : -__builtin_inff();
            float t1 = (key1 <= qrow) ? s[1][r] * SC : -__builtin_inff();
            float mt = fmaxf(t0, t1);
#pragma unroll
            for (int msk = 1; msk < 16; msk <<= 1) mt = fmaxf(mt, __shfl_xor(mt, msk));
            const float mn = fmaxf(m_r[r], mt);
            corr[r] = exp2f(m_r[r] - mn);
            m_r[r]  = mn;
            p0[r] = exp2f(t0 - mn);
            p1[r] = exp2f(t1 - mn);
            float rs = p0[r] + p1[r];
#pragma unroll
            for (int msk = 1; msk < 16; msk <<= 1) rs += __shfl_xor(rs, msk);
            l_r[r] = l_r[r] * corr[r] + rs;
        }
#pragma unroll
        for (int c = 0; c < 4; c++)
#pragma unroll
            for (int r = 0; r < 4; r++) o[c][r] *= corr[r];

        // ---- P -> LDS (per-wave), reread as A-fragment ----
#pragma unroll
        for (int r = 0; r < 4; r++) {
            const int row = (lane >> 4) * 4 + r;
            plds[w][row][lane & 15]        = (_Float16)p0[r];
            plds[w][row][16 + (lane & 15)] = (_Float16)p1[r];
        }
        half8 pa = *(const half8*)&plds[w][lane & 15][(lane >> 4) * 8];

        // ---- PV ----
#pragma unroll
        for (int c = 0; c < 4; c++) {
            half8 bv_ = *(const half8*)&vt[16 * c + (lane & 15)][(lane >> 4) * 8];
            o[c] = mfma_16x16x32(pa, bv_, o[c]);
        }
        __syncthreads();
    }

    // ---- epilogue ----
#pragma unroll
    for (int c = 0; c < 4; c++) {
#pragma unroll
        for (int r = 0; r < 4; r++) {
            const int row = q0 + 16 * w + (lane >> 4) * 4 + r;
            const float val = o[c][r] / l_r[r];
            out[(size_t)(b * S_LEN + row) * HD + 16 * c + (lane & 15)] = val;
        }
    }
}

extern "C" void kernel_launch(void* const* d_in, const int* in_sizes, int n_in,
                              void* d_out, int out_size, void* d_ws, size_t ws_size,
                              hipStream_t stream) {
    const float* x  = (const float*)d_in[0];
    const float* Wq = (const float*)d_in[1];
    const float* bq = (const float*)d_in[2];
    const float* Wk = (const float*)d_in[3];
    const float* bk = (const float*)d_in[4];
    const float* Wv = (const float*)d_in[5];
    const float* bv = (const float*)d_in[6];
    float* out = (float*)d_out;

    _Float16* ws = (_Float16*)d_ws;
    const size_t n = (size_t)NROW * HD;
    _Float16* qh = ws;
    _Float16* ql = qh + n;
    _Float16* kh = ql + n;
    _Float16* kl = kh + n;
    _Float16* vh = kl + n;

    proj_kernel<<<dim3(NROW / 64, 3), 256, 0, stream>>>(
        x, Wq, bq, Wk, bk, Wv, bv, qh, ql, kh, kl, vh);
    attn_kernel<<<dim3(S_LEN / 64, NB), 256, 0, stream>>>(
        qh, ql, kh, kl, vh, out);
}

// Round 2
// 87.075 us; speedup vs baseline: 1.4896x; 1.4896x over previous
//
#include <hip/hip_runtime.h>
#include <math.h>

#define S_LEN 2048
#define NB 4
#define EMB 1024
#define HD 64
#define NROW (NB * S_LEN)

typedef _Float16 half8 __attribute__((ext_vector_type(8)));
typedef _Float16 half4 __attribute__((ext_vector_type(4)));
typedef float f32x4 __attribute__((ext_vector_type(4)));

static __device__ __forceinline__ f32x4 mfma16(half8 a, half8 b, f32x4 c) {
    return __builtin_amdgcn_mfma_f32_16x16x32_f16(a, b, c, 0, 0, 0);
}

// ---------------------------------------------------------------------------
// prep_w: transpose+split W -> W^T hi/lo fp16, layout [192][1024]
// row gcol = mat*64 + col.  grid 192 blocks x 256 thr.
// ---------------------------------------------------------------------------
__global__ __launch_bounds__(256) void prep_w(
    const float* __restrict__ Wq, const float* __restrict__ Wk,
    const float* __restrict__ Wv,
    _Float16* __restrict__ wt_h, _Float16* __restrict__ wt_l)
{
    const int gcol = blockIdx.x;            // 0..191
    const int g = gcol >> 6, c = gcol & 63;
    const float* W = (g == 0) ? Wq : (g == 1) ? Wk : Wv;
#pragma unroll
    for (int i = 0; i < 4; i++) {
        const int k = threadIdx.x + 256 * i;
        const float v = W[(size_t)k * HD + c];
        const _Float16 h = (_Float16)v;
        wt_h[(size_t)gcol * EMB + k] = h;
        wt_l[(size_t)gcol * EMB + k] = (_Float16)(v - (float)h);
    }
}

// ---------------------------------------------------------------------------
// proj_kernel: fused q,k,v projection. 32 rows/block, 256 blocks, 4 waves.
// Wave w owns col-fragments f = 3w..3w+2 (f = mat*4 + c4).
// Register-prefetch of next K-tile (BK=32) hides global latency.
// Outputs: qh/ql, kh/kl row-major [8192][64]; v as V^T [4][64][2048] fp16.
// ---------------------------------------------------------------------------
__global__ __launch_bounds__(256) void proj_kernel(
    const float* __restrict__ x,
    const _Float16* __restrict__ wt_h, const _Float16* __restrict__ wt_l,
    const float* __restrict__ bq, const float* __restrict__ bk,
    const float* __restrict__ bv,
    _Float16* __restrict__ qh, _Float16* __restrict__ ql,
    _Float16* __restrict__ kh, _Float16* __restrict__ kl,
    _Float16* __restrict__ vt)
{
    const int m0   = blockIdx.x * 32;
    const int t    = threadIdx.x;
    const int lane = t & 63;
    const int w    = t >> 6;

    __shared__ __align__(16) _Float16 xh[32][40], xl[32][40];
    __shared__ __align__(16) _Float16 wth[192][40], wtl[192][40];

    const int xr = t >> 3;            // x row 0..31
    const int xk = (t & 7) * 4;       // x k-chunk (4 floats)

    f32x4 acc[2][3];
#pragma unroll
    for (int s = 0; s < 2; s++)
#pragma unroll
        for (int j = 0; j < 3; j++) acc[s][j] = f32x4{0, 0, 0, 0};

    // prefetch tile 0
    f32x4 xv = *(const f32x4*)(x + (size_t)(m0 + xr) * EMB + xk);
    half8 wvh[3], wvl[3];
#pragma unroll
    for (int j = 0; j < 3; j++) {
        const int cc = t + 256 * j, wrow = cc >> 2, wko = (cc & 3) * 8;
        wvh[j] = *(const half8*)(wt_h + (size_t)wrow * EMB + wko);
        wvl[j] = *(const half8*)(wt_l + (size_t)wrow * EMB + wko);
    }

    for (int ks = 0; ks < EMB / 32; ks++) {
        // ---- staged regs -> LDS ----
        half4 hx, lx;
#pragma unroll
        for (int i = 0; i < 4; i++) {
            const _Float16 h = (_Float16)xv[i];
            hx[i] = h;
            lx[i] = (_Float16)(xv[i] - (float)h);
        }
        *(half4*)&xh[xr][xk] = hx;
        *(half4*)&xl[xr][xk] = lx;
#pragma unroll
        for (int j = 0; j < 3; j++) {
            const int cc = t + 256 * j, wrow = cc >> 2, wko = (cc & 3) * 8;
            *(half8*)&wth[wrow][wko] = wvh[j];
            *(half8*)&wtl[wrow][wko] = wvl[j];
        }
        __syncthreads();

        // ---- prefetch next tile into regs ----
        if (ks + 1 < EMB / 32) {
            const int k0 = (ks + 1) * 32;
            xv = *(const f32x4*)(x + (size_t)(m0 + xr) * EMB + k0 + xk);
#pragma unroll
            for (int j = 0; j < 3; j++) {
                const int cc = t + 256 * j, wrow = cc >> 2, wko = (cc & 3) * 8;
                wvh[j] = *(const half8*)(wt_h + (size_t)wrow * EMB + k0 + wko);
                wvl[j] = *(const half8*)(wt_l + (size_t)wrow * EMB + k0 + wko);
            }
        }

        // ---- compute ----
        half8 axh[2], axl[2];
#pragma unroll
        for (int s = 0; s < 2; s++) {
            axh[s] = *(const half8*)&xh[16 * s + (lane & 15)][(lane >> 4) * 8];
            axl[s] = *(const half8*)&xl[16 * s + (lane & 15)][(lane >> 4) * 8];
        }
#pragma unroll
        for (int j = 0; j < 3; j++) {
            const int gcol = (w * 3 + j) * 16 + (lane & 15);
            const half8 bwh = *(const half8*)&wth[gcol][(lane >> 4) * 8];
            const half8 bwl = *(const half8*)&wtl[gcol][(lane >> 4) * 8];
#pragma unroll
            for (int s = 0; s < 2; s++) {
                acc[s][j] = mfma16(axh[s], bwh, acc[s][j]);
                acc[s][j] = mfma16(axh[s], bwl, acc[s][j]);
                acc[s][j] = mfma16(axl[s], bwh, acc[s][j]);
            }
        }
        __syncthreads();
    }

    // ---- epilogue ----
#pragma unroll
    for (int j = 0; j < 3; j++) {
        const int f = w * 3 + j, mat = f >> 2, c4 = f & 3;
        const int mcol = c4 * 16 + (lane & 15);
        const float* bias = (mat == 0) ? bq : (mat == 1) ? bk : bv;
        const float bb = bias[mcol];
#pragma unroll
        for (int s = 0; s < 2; s++) {
            const int grow0 = m0 + 16 * s + (lane >> 4) * 4;
            if (mat == 2) {
                half4 hv;
#pragma unroll
                for (int r = 0; r < 4; r++) hv[r] = (_Float16)(acc[s][j][r] + bb);
                const int b = grow0 >> 11, sr = grow0 & (S_LEN - 1);
                *(half4*)(vt + ((size_t)b * HD + mcol) * S_LEN + sr) = hv;
            } else {
                _Float16* oh = (mat == 0) ? qh : kh;
                _Float16* ol = (mat == 0) ? ql : kl;
#pragma unroll
                for (int r = 0; r < 4; r++) {
                    const float val = acc[s][j][r] + bb;
                    const _Float16 h = (_Float16)val;
                    oh[(size_t)(grow0 + r) * HD + mcol] = h;
                    ol[(size_t)(grow0 + r) * HD + mcol] = (_Float16)(val - (float)h);
                }
            }
        }
    }
}

// ---------------------------------------------------------------------------
// attn_kernel: causal flash attention, QB=16 rows/block, grid (128, 4).
// The 4 waves split KV tiles (stride 4), private (m,l,o), merged via LDS at
// the end.  No barriers in the K-loop.  K read global->regs; V^T from global.
// ---------------------------------------------------------------------------
#define SC 11.5415603f /* 8 * log2(e) */

__global__ __launch_bounds__(256) void attn_kernel(
    const _Float16* __restrict__ qh, const _Float16* __restrict__ ql,
    const _Float16* __restrict__ kh, const _Float16* __restrict__ kl,
    const _Float16* __restrict__ vt, float* __restrict__ out)
{
    const int b    = blockIdx.y;
    const int qt   = (int)(gridDim.x - 1 - blockIdx.x);  // long blocks first
    const int q0   = qt * 16;
    const int t    = threadIdx.x;
    const int lane = t & 63;
    const int w    = t >> 6;

    __shared__ __align__(16) _Float16 plds[4][16][40];
    __shared__ __align__(16) float obuf[4][16][68];
    __shared__ float mbuf[4][16], lbuf[4][16];

    // Q A-fragments (all waves: same 16 rows)
    const size_t rowq = ((size_t)b * S_LEN + q0 + (lane & 15)) * HD;
    half8 aqh[2], aql[2];
#pragma unroll
    for (int h = 0; h < 2; h++) {
        aqh[h] = *(const half8*)(qh + rowq + h * 32 + (lane >> 4) * 8);
        aql[h] = *(const half8*)(ql + rowq + h * 32 + (lane >> 4) * 8);
    }

    f32x4 o[4];
#pragma unroll
    for (int c = 0; c < 4; c++) o[c] = f32x4{0, 0, 0, 0};
    float m_r[4], l_r[4];
#pragma unroll
    for (int r = 0; r < 4; r++) { m_r[r] = -__builtin_inff(); l_r[r] = 0.f; }

    const int nt = (q0 + 16 + 31) / 32;
    const size_t kbase = (size_t)b * S_LEN * HD;
    const size_t vbase = (size_t)b * HD * S_LEN;

    for (int tile = w; tile < nt; tile += 4) {
        const int kv0 = tile * 32;

        // V^T B-fragments (issue first; used last)
        half8 vf[4];
#pragma unroll
        for (int c = 0; c < 4; c++)
            vf[c] = *(const half8*)(vt + vbase +
                     (size_t)(16 * c + (lane & 15)) * S_LEN + kv0 + (lane >> 4) * 8);

        // K B-fragments
        half8 bh[2][2], bl[2][2];
#pragma unroll
        for (int f = 0; f < 2; f++) {
            const size_t kr = kbase + (size_t)(kv0 + 16 * f + (lane & 15)) * HD + (lane >> 4) * 8;
            bh[f][0] = *(const half8*)(kh + kr);
            bl[f][0] = *(const half8*)(kl + kr);
            bh[f][1] = *(const half8*)(kh + kr + 32);
            bl[f][1] = *(const half8*)(kl + kr + 32);
        }

        // QK^T (3-term split precision)
        f32x4 s01[2] = {f32x4{0, 0, 0, 0}, f32x4{0, 0, 0, 0}};
#pragma unroll
        for (int f = 0; f < 2; f++)
#pragma unroll
            for (int h = 0; h < 2; h++) {
                s01[f] = mfma16(aqh[h], bh[f][h], s01[f]);
                s01[f] = mfma16(aqh[h], bl[f][h], s01[f]);
                s01[f] = mfma16(aql[h], bh[f][h], s01[f]);
            }

        // mask + online softmax (scaled-log2 units)
        const bool masked = (kv0 + 31 > q0);
        float p0[4], p1[4], corr[4];
#pragma unroll
        for (int r = 0; r < 4; r++) {
            const int qrow = q0 + (lane >> 4) * 4 + r;
            float t0 = s01[0][r] * SC;
            float t1 = s01[1][r] * SC;
            if (masked) {
                if (kv0 + (lane & 15) > qrow)      t0 = -__builtin_inff();
                if (kv0 + 16 + (lane & 15) > qrow) t1 = -__builtin_inff();
            }
            float mt = fmaxf(t0, t1);
#pragma unroll
            for (int msk = 1; msk < 16; msk <<= 1) mt = fmaxf(mt, __shfl_xor(mt, msk));
            const float mn = fmaxf(m_r[r], mt);
            corr[r] = exp2f(m_r[r] - mn);
            m_r[r]  = mn;
            p0[r] = exp2f(t0 - mn);
            p1[r] = exp2f(t1 - mn);
            float rs = p0[r] + p1[r];
#pragma unroll
            for (int msk = 1; msk < 16; msk <<= 1) rs += __shfl_xor(rs, msk);
            l_r[r] = l_r[r] * corr[r] + rs;
        }
#pragma unroll
        for (int c = 0; c < 4; c++)
#pragma unroll
            for (int r = 0; r < 4; r++) o[c][r] *= corr[r];

        // P -> wave-private LDS -> A-fragment
#pragma unroll
        for (int r = 0; r < 4; r++) {
            const int row = (lane >> 4) * 4 + r;
            plds[w][row][lane & 15]        = (_Float16)p0[r];
            plds[w][row][16 + (lane & 15)] = (_Float16)p1[r];
        }
        const half8 pa = *(const half8*)&plds[w][lane & 15][(lane >> 4) * 8];

        // PV
#pragma unroll
        for (int c = 0; c < 4; c++) o[c] = mfma16(pa, vf[c], o[c]);
    }

    // ---- merge the 4 waves' partial softmax states ----
    if ((lane & 15) == 0) {
#pragma unroll
        for (int r = 0; r < 4; r++) {
            const int row = (lane >> 4) * 4 + r;
            mbuf[w][row] = m_r[r];
            lbuf[w][row] = l_r[r];
        }
    }
#pragma unroll
    for (int c = 0; c < 4; c++)
#pragma unroll
        for (int r = 0; r < 4; r++)
            obuf[w][(lane >> 4) * 4 + r][16 * c + (lane & 15)] = o[c][r];
    __syncthreads();

    {
        const int row = t >> 4;        // 0..15
        const int cb  = (t & 15) * 4;  // col base 0..60
        float M = fmaxf(fmaxf(mbuf[0][row], mbuf[1][row]),
                        fmaxf(mbuf[2][row], mbuf[3][row]));
        float ew[4], L = 0.f;
#pragma unroll
        for (int w2 = 0; w2 < 4; w2++) {
            ew[w2] = exp2f(mbuf[w2][row] - M);
            L += lbuf[w2][row] * ew[w2];
        }
        f32x4 acc = f32x4{0, 0, 0, 0};
#pragma unroll
        for (int w2 = 0; w2 < 4; w2++) {
            const f32x4 ov = *(const f32x4*)&obuf[w2][row][cb];
#pragma unroll
            for (int jj = 0; jj < 4; jj++) acc[jj] += ov[jj] * ew[w2];
        }
        const float inv = 1.0f / L;
        f32x4 res;
#pragma unroll
        for (int jj = 0; jj < 4; jj++) res[jj] = acc[jj] * inv;
        *(f32x4*)(out + ((size_t)b * S_LEN + q0 + row) * HD + cb) = res;
    }
}

extern "C" void kernel_launch(void* const* d_in, const int* in_sizes, int n_in,
                              void* d_out, int out_size, void* d_ws, size_t ws_size,
                              hipStream_t stream) {
    const float* x  = (const float*)d_in[0];
    const float* Wq = (const float*)d_in[1];
    const float* bq = (const float*)d_in[2];
    const float* Wk = (const float*)d_in[3];
    const float* bk = (const float*)d_in[4];
    const float* Wv = (const float*)d_in[5];
    const float* bv = (const float*)d_in[6];
    float* out = (float*)d_out;

    _Float16* ws = (_Float16*)d_ws;
    const size_t nW = (size_t)192 * EMB;     // 196608
    const size_t n  = (size_t)NROW * HD;     // 524288
    _Float16* wt_h = ws;
    _Float16* wt_l = wt_h + nW;
    _Float16* qh = wt_l + nW;
    _Float16* ql = qh + n;
    _Float16* kh = ql + n;
    _Float16* kl = kh + n;
    _Float16* vt = kl + n;

    prep_w<<<192, 256, 0, stream>>>(Wq, Wk, Wv, wt_h, wt_l);
    proj_kernel<<<NROW / 32, 256, 0, stream>>>(
        x, wt_h, wt_l, bq, bk, bv, qh, ql, kh, kl, vt);
    attn_kernel<<<dim3(S_LEN / 16, NB), 256, 0, stream>>>(
        qh, ql, kh, kl, vt, out);
}